// Round 1
// baseline (301.805 us; speedup 1.0000x reference)
//
#include <hip/hip_runtime.h>

// VQ-VAE quantizer, MI355X — fp32 I/O. 3 launches:
//   prep      : blocks 0..255  -> codebook to bf16 MFMA-B-fragment layout + fp32 wnorm
//                                 (block 0 zeroes accum/hist)
//               blocks 256..383-> M2T[o][e] = <w_e, conv_w_o> + conv_b[o] in exact fp32
//                                 (recomputed from emb directly: NO dependency on wfrag,
//                                  so both halves of the grid overlap; 512 waves vs the
//                                  old 16-wave latency-bound prep_m)
//   argmin_out: pipelined MFMA distance GEMM (VGPR prefetch across barrier, dbuf LDS,
//               pos-major swizzled A-tile -> ds_read_b128 frags) + fused z^2/d_min/hist
//               + FUSED output write: out[b][o][p0..p0+127] = M2T[o][idx[p]] gathered
//               from L2 (no idxs round trip, no separate 128MB-write kernel ramp)
//   fin_k     : 1 block; loss + perplexity scalars from accum/hist

#define C_DIM 512
#define N_E   256
#define HW    4096
#define SAr   72    // A_lds row stride in u16 (64 + 8 pad): 16B-aligned rows for ds_read_b128

typedef unsigned short u16;
typedef u16   u16x4 __attribute__((ext_vector_type(4)));
typedef u16   u16x8 __attribute__((ext_vector_type(8)));
typedef short s16x8 __attribute__((ext_vector_type(8)));   // bf16 MFMA fragment (4 VGPRs)
typedef float f32x4 __attribute__((ext_vector_type(4)));

__device__ __forceinline__ u16 f2bf(float f) {
    unsigned u = __float_as_uint(f);
    return (u16)((u + 0x7FFFu + ((u >> 16) & 1u)) >> 16);   // RNE
}

// ---------------- prep: wfrag/wnorm (blocks <256) + fp32 M2T (blocks >=256) --
// wfrag element (code c, k): ntg=c>>4, lane=(c&15)|(((k>>3)&3)<<4), ksg=k>>5, j=k&7
__global__ __launch_bounds__(256)
void prep(const float* __restrict__ emb, const float* __restrict__ stdp,
          const float* __restrict__ means, const float* __restrict__ convw,
          const float* __restrict__ convb,
          u16* __restrict__ wfrag, float* __restrict__ wnorm,
          float* __restrict__ M2T, float* __restrict__ accum,
          unsigned int* __restrict__ hist) {
    int t = threadIdx.x;
    float stdv  = fabsf(stdp[0]);
    float meanv = (means[0] + means[1] + means[2]) * (1.0f / 3.0f);

    if (blockIdx.x < 256) {
        int c = blockIdx.x;          // code
        if (c == 0) {                // zero reduction scratch (re-poisoned each call)
            hist[t] = 0u;
            if (t < 2) accum[t] = 0.f;
        }
        float ss = 0.f;
        for (int k = t; k < C_DIM; k += 256) {
            float w = emb[c * C_DIM + k] * stdv + meanv;
            ss += w * w;                               // fp32 norm (matches np ref)
            int ntg  = c >> 4;
            int lane = (c & 15) | (((k >> 3) & 3) << 4);
            int ksg  = k >> 5;
            int j    = k & 7;
            wfrag[((ntg * 16 + ksg) * 64 + lane) * 8 + j] = f2bf(w);
        }
        #pragma unroll
        for (int m = 1; m < 64; m <<= 1) ss += __shfl_xor(ss, m, 64);
        __shared__ float red[4];
        if ((t & 63) == 0) red[t >> 6] = ss;
        __syncthreads();
        if (t == 0) wnorm[c] = red[0] + red[1] + red[2] + red[3];
    } else {
        // M2T block: 4 o-rows x 256 e, exact fp32. convw rows staged in LDS
        // (broadcast reads), each thread streams its emb row (L2-hot, 512KB table).
        __shared__ float cw[4][C_DIM];                 // 8 KB
        int o0 = (blockIdx.x - 256) * 4;
        for (int i = t; i < 4 * C_DIM; i += 256)
            cw[i >> 9][i & 511] = convw[(o0 + (i >> 9)) * C_DIM + (i & 511)];
        __syncthreads();
        float a0 = 0.f, a1 = 0.f, a2 = 0.f, a3 = 0.f;
        const float* er = emb + t * C_DIM;             // e = t
        #pragma unroll 4
        for (int k = 0; k < C_DIM; k += 4) {
            f32x4 ev = *(const f32x4*)(er + k);
            #pragma unroll
            for (int jj = 0; jj < 4; ++jj) {
                float w = ev[jj] * stdv + meanv;
                a0 += cw[0][k + jj] * w;
                a1 += cw[1][k + jj] * w;
                a2 += cw[2][k + jj] * w;
                a3 += cw[3][k + jj] * w;
            }
        }
        M2T[(o0 + 0) * N_E + t] = a0 + convb[o0 + 0];
        M2T[(o0 + 1) * N_E + t] = a1 + convb[o0 + 1];
        M2T[(o0 + 2) * N_E + t] = a2 + convb[o0 + 2];
        M2T[(o0 + 3) * N_E + t] = a3 + convb[o0 + 3];
    }
}

// ---------------- argmin_out: distance GEMM + argmin + fused out write -------
// Block: 128 pos x 256 codes, 4 waves (2 m-halves x 2 n-halves); K chunks of 64 ch.
// A-tile LDS: pos-major [pos][ch^swz], SAr=72; swz: ch8blk ^= ((pos>>3)&7)<<3.
__global__ __launch_bounds__(256, 2)
void argmin_out(const float* __restrict__ z, const u16* __restrict__ wfrag,
                const float* __restrict__ wnorm, const float* __restrict__ M2T,
                float* __restrict__ out,
                float* __restrict__ accum, unsigned int* __restrict__ hist) {
    __shared__ u16 Ab[2][128 * SAr];           // 2 x 18 KB
    __shared__ unsigned long long lmin[128];
    __shared__ unsigned int lhist[N_E];
    __shared__ float lred[8];
    __shared__ u16 lcode[128];

    int tid = threadIdx.x;
    int wave = tid >> 6, lane = tid & 63;
    int mhalf = wave & 1, nhalf = wave >> 1;
    int bb = blockIdx.x;                       // 512 blocks; b = bb>>5, p0 = (bb&31)*128
    const float* zb = z + (size_t)(bb >> 5) * (C_DIM * HW) + (bb & 31) * 128;

    if (tid < 128) lmin[tid] = ~0ull;
    lhist[tid] = 0u;

    f32x4 acc[4][8];
    #pragma unroll
    for (int mt = 0; mt < 4; ++mt)
        #pragma unroll
        for (int nt = 0; nt < 8; ++nt)
            acc[mt][nt] = (f32x4){0.f, 0.f, 0.f, 0.f};

    // staging: thread = (cg 0..7: 8-ch group, t5 0..31: 4-pos group)
    int t5 = tid & 31, cg = tid >> 5;
    const float* gsrc = zb + (size_t)(cg * 8) * HW + t5 * 4;
    int skey = (t5 >> 1) & 7;                  // == (pos>>3)&7 for this thread's 4 pos
    int wch  = (cg * 8) ^ (skey * 8);
    float zs = 0.f;

    int m15 = lane & 15, quad = lane >> 4;
    const u16x8* wf8 = (const u16x8*)wfrag;

    f32x4 sv[8];
    #pragma unroll
    for (int i = 0; i < 8; ++i) sv[i] = *(const f32x4*)(gsrc + (size_t)i * HW);
    // convert + store chunk 0 into buf 0
    #pragma unroll
    for (int p = 0; p < 4; ++p) {
        u16x8 pk;
        #pragma unroll
        for (int i = 0; i < 8; ++i) { float f = sv[i][p]; zs += f * f; pk[i] = f2bf(f); }
        *(u16x8*)(&Ab[0][(t5 * 4 + p) * SAr + wch]) = pk;
    }

    for (int kc = 0; kc < 8; ++kc) {
        int cur = kc & 1;
        if (kc < 7) {                           // prefetch next chunk (stays in flight
            const float* g2 = gsrc + (size_t)((kc + 1) * 64) * HW;  // across the barrier:
            #pragma unroll                      // no global stores in this loop)
            for (int i = 0; i < 8; ++i) sv[i] = *(const f32x4*)(g2 + (size_t)i * HW);
        }
        __syncthreads();                        // Ab[cur] ready for all waves
        #pragma unroll
        for (int ks = 0; ks < 2; ++ks) {
            s16x8 bfr[8];                       // B frags from global (L2-hot, 256 KB total)
            #pragma unroll
            for (int nt = 0; nt < 8; ++nt) {
                int ntg = nhalf * 8 + nt, ksg = kc * 2 + ks;
                bfr[nt] = __builtin_bit_cast(s16x8, wf8[(ntg * 16 + ksg) * 64 + lane]);
            }
            s16x8 am[4];                        // A frags: one ds_read_b128 each
            #pragma unroll
            for (int mt = 0; mt < 4; ++mt) {
                int pos = mhalf * 64 + mt * 16 + m15;
                int rkey = (mt * 2 + (m15 >> 3)) & 7;         // == (pos>>3)&7
                int rch = (ks * 32 + quad * 8) ^ (rkey * 8);
                am[mt] = __builtin_bit_cast(s16x8, *(const u16x8*)(&Ab[cur][pos * SAr + rch]));
            }
            #pragma unroll
            for (int mt = 0; mt < 4; ++mt)
                #pragma unroll
                for (int nt = 0; nt < 8; ++nt)
                    acc[mt][nt] = __builtin_amdgcn_mfma_f32_16x16x32_bf16(
                        am[mt], bfr[nt], acc[mt][nt], 0, 0, 0);
        }
        if (kc < 7) {                           // convert + store into other buffer
            #pragma unroll
            for (int p = 0; p < 4; ++p) {
                u16x8 pk;
                #pragma unroll
                for (int i = 0; i < 8; ++i) { float f = sv[i][p]; zs += f * f; pk[i] = f2bf(f); }
                *(u16x8*)(&Ab[cur ^ 1][(t5 * 4 + p) * SAr + wch]) = pk;
            }
        }
    }

    // ---- scoring: d = wnorm - 2*dot; argmin with lowest-index tie-break ----
    float wn[8];
    #pragma unroll
    for (int nt = 0; nt < 8; ++nt) wn[nt] = wnorm[(nhalf * 8 + nt) * 16 + m15];

    #pragma unroll
    for (int mt = 0; mt < 4; ++mt) {
        #pragma unroll
        for (int r = 0; r < 4; ++r) {
            unsigned long long key = ~0ull;
            #pragma unroll
            for (int nt = 0; nt < 8; ++nt) {
                float d = wn[nt] - 2.0f * acc[mt][nt][r];
                unsigned u = __float_as_uint(d);
                u ^= (u >> 31) ? 0xFFFFFFFFu : 0x80000000u;   // monotone float->uint
                unsigned code = (unsigned)((nhalf * 8 + nt) * 16 + m15);
                unsigned long long k2 = ((unsigned long long)u << 32) | code;
                key = (k2 < key) ? k2 : key;
            }
            #pragma unroll
            for (int sm = 1; sm < 16; sm <<= 1) {             // reduce across m15
                unsigned long long o2 = (unsigned long long)__shfl_xor((long long)key, sm, 64);
                key = (o2 < key) ? o2 : key;
            }
            if (m15 == 0) {
                int pos = mhalf * 64 + mt * 16 + quad * 4 + r;
                atomicMin(&lmin[pos], key);
            }
        }
    }
    __syncthreads();

    float dsum = 0.f;
    if (tid < 128) {
        unsigned long long key = lmin[tid];
        unsigned code = (unsigned)(key & 0xFFFFu);
        unsigned u = (unsigned)(key >> 32);
        u ^= (u >> 31) ? 0x80000000u : 0xFFFFFFFFu;           // inverse transform
        dsum = __uint_as_float(u);
        lcode[tid] = (u16)code;
        atomicAdd(&lhist[code], 1u);
    }
    #pragma unroll
    for (int sm = 1; sm < 64; sm <<= 1) {
        dsum += __shfl_xor(dsum, sm, 64);
        zs   += __shfl_xor(zs, sm, 64);
    }
    if (lane == 0) { lred[wave] = dsum; lred[4 + wave] = zs; }
    __syncthreads();                           // lcode/lhist/lred all visible
    if (tid == 0) {
        atomicAdd(&accum[0], lred[4] + lred[5] + lred[6] + lred[7]);  // Sum z^2
        atomicAdd(&accum[1], lred[0] + lred[1] + lred[2] + lred[3]);  // Sum d_min
    }
    unsigned cnt = lhist[tid];
    if (cnt) atomicAdd(&hist[tid], cnt);

    // ---- fused out write: out[b][o][p0+0..127] = M2T[o][code[p]] -----------
    // thread = (t5o 0..31: 4-pos group, oo 0..7: o-lane); per og-pass a wave
    // writes two 512B-contiguous segments; gathers are 4B random within one
    // 1KB L2-hot M2T row (line-coalesced ~4x).
    int t5o = tid & 31, oo = tid >> 5;
    int ec[4];
    #pragma unroll
    for (int jj = 0; jj < 4; ++jj) ec[jj] = (int)lcode[t5o * 4 + jj];
    float* obase = out + ((size_t)(bb >> 5) * C_DIM + oo) * HW + (bb & 31) * 128 + t5o * 4;
    const float* m2 = M2T + oo * N_E;
    #pragma unroll 4
    for (int og = 0; og < C_DIM; og += 8) {
        f32x4 r;
        #pragma unroll
        for (int jj = 0; jj < 4; ++jj) r[jj] = m2[og * N_E + ec[jj]];
        *(f32x4*)(obase + (size_t)og * HW) = r;
    }
}

// ---------------- fin_k: loss + perplexity scalars ---------------------------
__global__ __launch_bounds__(256)
void fin_k(const float* __restrict__ accum, const unsigned int* __restrict__ hist,
           float* __restrict__ out) {
    int tid = threadIdx.x;
    float e = (float)hist[tid] * (1.0f / 65536.0f);
    float term = e * logf(e + 1e-10f);
    #pragma unroll
    for (int m = 1; m < 64; m <<= 1) term += __shfl_xor(term, m, 64);
    __shared__ float red[4];
    if ((tid & 63) == 0) red[tid >> 6] = term;
    __syncthreads();
    if (tid == 0) {
        float s = red[0] + red[1] + red[2] + red[3];
        out[33554432] = 1.25f * (accum[0] + accum[1]) * (1.0f / 33554432.0f);
        out[33554433] = expf(-s);
    }
}

extern "C" void kernel_launch(void* const* d_in, const int* in_sizes, int n_in,
                              void* d_out, int out_size, void* d_ws, size_t ws_size,
                              hipStream_t stream) {
    (void)in_sizes; (void)n_in; (void)out_size; (void)ws_size;
    const float* z     = (const float*)d_in[0];   // [16][512][64][64] fp32
    const float* emb   = (const float*)d_in[1];   // [256][512] fp32
    const float* stdp  = (const float*)d_in[2];   // scalar
    const float* means = (const float*)d_in[3];   // [3]
    const float* convw = (const float*)d_in[4];   // [512][512] fp32
    const float* convb = (const float*)d_in[5];   // [512]

    char* ws = (char*)d_ws;
    u16*   wfrag = (u16*)(ws + 0);            // 262144 B (bf16 B-fragments)
    float* wnorm = (float*)(ws + 262144);     // 1024 B
    float* M2T   = (float*)(ws + 263168);     // 524288 B  [o][e] fp32
    float* accum = (float*)(ws + 787456);     // 8 B  [zsq, dsum]
    unsigned int* hist = (unsigned int*)(ws + 787464);  // 1024 B
    float* out = (float*)d_out;

    prep      <<<384, 256, 0, stream>>>(emb, stdp, means, convw, convb,
                                        wfrag, wnorm, M2T, accum, hist);
    argmin_out<<<512, 256, 0, stream>>>(z, wfrag, wnorm, M2T, out, accum, hist);
    fin_k     <<<1,   256, 0, stream>>>(accum, hist, out);
}